// Round 3
// baseline (1055.302 us; speedup 1.0000x reference)
//
#include <hip/hip_runtime.h>
#include <hip/hip_bf16.h>

#define NN 500000
#define EE 2000000
#define GG 16384
#define ND 44
#define ED 12
#define HH 64
#define EMB 128
#define NBLK 123          // ceil(NN / 4096) scan blocks
#define NTILE (NN / 16)   // 31250, exact

typedef __attribute__((ext_vector_type(8))) short bf16x8;
typedef __attribute__((ext_vector_type(4))) float f32x4;

// fp32 -> bf16 round-to-nearest-even, bit pattern as short
__device__ inline short f2bf(float v) {
    unsigned int x = __builtin_bit_cast(unsigned int, v);
    x += 0x7FFFu + ((x >> 16) & 1u);
    return (short)(x >> 16);
}
// fp32 <-> fp16 (RNE, v_cvt_f16_f32 / v_cvt_f32_f16)
__device__ inline unsigned short f2h(float v) {
    return __builtin_bit_cast(unsigned short, (_Float16)v);
}
__device__ inline float h2f(unsigned short s) {
    return (float)__builtin_bit_cast(_Float16, s);
}
__device__ inline unsigned pkh(float a, float b) {
    return (unsigned)f2h(a) | ((unsigned)f2h(b) << 16);
}
__device__ inline float2 upk(unsigned u) {
    return make_float2((float)__builtin_bit_cast(_Float16, (unsigned short)(u & 0xffffu)),
                       (float)__builtin_bit_cast(_Float16, (unsigned short)(u >> 16)));
}

// Wave-local LDS ordering fence (per-wave LDS buffers; does NOT drain vmcnt).
__device__ inline void wave_lds_fence() {
    asm volatile("s_waitcnt lgkmcnt(0)" ::: "memory");
    __builtin_amdgcn_sched_barrier(0);
}

// ---------------------------------------------------------------------------
// Weight prep: transpose to [n][k] layout, cast to bf16, zero-pad K of w1a to 64
__global__ __launch_bounds__(256) void prep_weights(
    const float* __restrict__ w1a, const float* __restrict__ w1b,
    const float* __restrict__ w2a, const float* __restrict__ w2b,
    short* __restrict__ o) {
    int t = blockIdx.x * 256 + threadIdx.x;
    if (t < 4096) {
        int n = t >> 6, k = t & 63;
        o[t] = f2bf(k < ND ? w1a[k * HH + n] : 0.f);
    } else if (t < 8192) {
        int u = t - 4096; int n = u >> 6, k = u & 63;
        o[t] = f2bf(w1b[k * HH + n]);
    } else if (t < 16384) {
        int u = t - 8192; int n = u >> 6, k = u & 63;
        o[t] = f2bf(w2a[k * EMB + n]);
    } else if (t < 32768) {
        int u = t - 16384; int n = u >> 7, k = u & 127;
        o[t] = f2bf(w2b[k * EMB + n]);
    }
}

// ---------------------------------------------------------------------------
// CSR build: histogram of dst, exclusive scan, scatter by dst.
__global__ __launch_bounds__(256) void hist_kernel(const int* __restrict__ ei,
                                                   int* __restrict__ deg) {
    int e = blockIdx.x * 256 + threadIdx.x;
    if (e < EE) atomicAdd(&deg[ei[EE + e]], 1);
}

__global__ __launch_bounds__(256) void scan_reduce(const int* __restrict__ deg,
                                                   int* __restrict__ bsum) {
    int b = blockIdx.x, t = threadIdx.x;
    int base = b * 4096;
    int s = 0;
    for (int i = t; i < 4096; i += 256) {
        int g = base + i;
        if (g < NN) s += deg[g];
    }
#pragma unroll
    for (int off = 32; off; off >>= 1) s += __shfl_xor(s, off);
    __shared__ int ws[4];
    if ((t & 63) == 0) ws[t >> 6] = s;
    __syncthreads();
    if (t == 0) bsum[b] = ws[0] + ws[1] + ws[2] + ws[3];
}

__global__ __launch_bounds__(128) void scan_mid(const int* __restrict__ bsum,
                                                int* __restrict__ boff,
                                                int* __restrict__ rowptr) {
    int t = threadIdx.x;
    int v = (t < NBLK) ? bsum[t] : 0;
    int x = v;
#pragma unroll
    for (int off = 1; off < 64; off <<= 1) {
        int y = __shfl_up(x, off);
        if ((t & 63) >= off) x += y;
    }
    __shared__ int wt[2];
    if ((t & 63) == 63) wt[t >> 6] = x;
    __syncthreads();
    int xx = x + ((t >= 64) ? wt[0] : 0);
    if (t < NBLK) boff[t] = xx - v;
    if (t == 127) rowptr[NN] = xx;
}

__global__ __launch_bounds__(256) void scan_final(const int* __restrict__ deg,
                                                  const int* __restrict__ boff,
                                                  int* __restrict__ rowptr,
                                                  int* __restrict__ cursor) {
    int b = blockIdx.x, t = threadIdx.x;
    int base = b * 4096 + t * 16;
    int loc[16];
    int s = 0;
#pragma unroll
    for (int j = 0; j < 16; ++j) {
        int g = base + j;
        loc[j] = (g < NN) ? deg[g] : 0;
        s += loc[j];
    }
    int xinc = s;
#pragma unroll
    for (int off = 1; off < 64; off <<= 1) {
        int y = __shfl_up(xinc, off);
        if ((t & 63) >= off) xinc += y;
    }
    __shared__ int wt[4];
    if ((t & 63) == 63) wt[t >> 6] = xinc;
    __syncthreads();
    int wv = t >> 6, woff = 0;
#pragma unroll
    for (int k = 0; k < 4; ++k)
        if (k < wv) woff += wt[k];
    int run = boff[b] + woff + (xinc - s);
#pragma unroll
    for (int j = 0; j < 16; ++j) {
        int g = base + j;
        if (g < NN) { rowptr[g] = run; cursor[g] = run; }
        run += loc[j];
    }
}

// Scatter: build 32B CSR rows: [12 x fp16 edge-attr (24B) | src int (4B) | pad].
// 32B-aligned writes never straddle a 64B line and match the HBM3 32B write
// sector -> no partial-line RMW (round-2's 282MB WRITE_SIZE pathology).
__global__ __launch_bounds__(256) void scatter_kernel(const int* __restrict__ ei,
                                                      const float* __restrict__ ea,
                                                      int* __restrict__ cursor,
                                                      unsigned int* __restrict__ csr) {
    int e = blockIdx.x * 256 + threadIdx.x;
    if (e < EE) {
        int dst = ei[EE + e];
        const float4* s = (const float4*)(ea + (size_t)e * ED);
        float4 a0 = s[0], a1 = s[1], a2 = s[2];
        uint4 P0, P1;
        P0.x = pkh(a0.x, a0.y); P0.y = pkh(a0.z, a0.w);
        P0.z = pkh(a1.x, a1.y); P0.w = pkh(a1.z, a1.w);
        P1.x = pkh(a2.x, a2.y); P1.y = pkh(a2.z, a2.w);
        P1.z = (unsigned)ei[e];   // src at word 6
        P1.w = 0u;
        int pos = atomicAdd(&cursor[dst], 1);
        uint4* d = (uint4*)(csr + (size_t)pos * 8);
        d[0] = P0; d[1] = P1;
    }
}

// ---------------------------------------------------------------------------
// Gather aggregation, 8 nodes/wave, fused skip-add + bf16 output:
//   out16[i][0:64] = bf16( xf[i] + sum_{e: dst=i} relu(xf[src] + ea@W + b) )
// CSR rows are 32B (fp16 attrs + src). Layer 1 reads x (f32, stride ND);
// layer 2 reads hbuf (fp16, stride HH). 8-deep software pipeline with attrs
// kept PACKED in the pipeline registers (6 u32/slot), unpacked at consume.
template <int D>
__global__ __launch_bounds__(256) void agg_gather(
    const float* __restrict__ xf32, const unsigned short* __restrict__ xf16,
    const unsigned int* __restrict__ cea,
    const float* __restrict__ ew, const float* __restrict__ eb,
    const int* __restrict__ rowptr,
    short* __restrict__ out) {
    int lane = threadIdx.x & 63;
    int wv = threadIdx.x >> 6;
    int i0 = (blockIdx.x * 4 + wv) * 8;
    if (i0 >= NN) return;
    float w0, w1, w2, w3, w4, w5, w6, w7, w8, w9, w10, w11, breg;
    if (D == 64 || lane < D) {
        w0 = ew[0 * D + lane];  w1 = ew[1 * D + lane];  w2 = ew[2 * D + lane];
        w3 = ew[3 * D + lane];  w4 = ew[4 * D + lane];  w5 = ew[5 * D + lane];
        w6 = ew[6 * D + lane];  w7 = ew[7 * D + lane];  w8 = ew[8 * D + lane];
        w9 = ew[9 * D + lane];  w10 = ew[10 * D + lane]; w11 = ew[11 * D + lane];
        breg = eb[lane];
    } else {
        w0=w1=w2=w3=w4=w5=w6=w7=w8=w9=w10=w11=0.f; breg = 0.f;
    }
    int rp = (lane <= 8) ? rowptr[i0 + lane] : 0;
    int beg = __builtin_amdgcn_readfirstlane(__builtin_amdgcn_readlane(rp, 0));
    int end = __builtin_amdgcn_readfirstlane(__builtin_amdgcn_readlane(rp, 8));
    // coalesced preload of this wave's src words (first 128 CSR entries);
    // also warms the L2 lines the packed-attr reads will hit.
    int s0 = 0, s1 = 0;
    if (beg + lane < end) s0 = (int)cea[(size_t)(beg + lane) * 8 + 6];
    if (beg + 64 + lane < end) s1 = (int)cea[(size_t)(beg + 64 + lane) * 8 + 6];

    auto SKIPLD = [&](int j) -> float {
        if (D == HH) return h2f(xf16[(size_t)(i0 + j) * HH + lane]);
        return (lane < D) ? xf32[(size_t)(i0 + j) * ND + lane] : 0.f;
    };

    float acc = 0.f;
    int np = 0;
    int nb = __builtin_amdgcn_readlane(rp, 1);
    float sk = SKIPLD(0);
    // flush leading empty nodes (boundary == beg)
    while (np < 8 && nb == beg) {
        out[(size_t)(i0 + np) * 64 + lane] = f2bf(sk);   // acc == 0
        ++np;
        nb = (np < 8) ? __builtin_amdgcn_readlane(rp, np + 1) : 0x7fffffff;
        sk = (np < 8) ? SKIPLD(np) : 0.f;
    }

    auto LOADE = [&](int pos, uint4& P0, uint2& P1, float& XV) {
        if (pos < end) {
            int off = pos - beg;
            int src;
            if (off < 64)       src = __builtin_amdgcn_readlane(s0, off);
            else if (off < 128) src = __builtin_amdgcn_readlane(s1, off - 64);
            else                src = __builtin_amdgcn_readfirstlane((int)cea[(size_t)pos * 8 + 6]);
            P0 = *(const uint4*)(cea + (size_t)pos * 8);
            P1 = *(const uint2*)(cea + (size_t)pos * 8 + 4);
            if (D == HH) XV = h2f(xf16[(size_t)src * HH + lane]);
            else         XV = (lane < D) ? xf32[(size_t)src * ND + lane] : 0.f;
        }
    };
    auto CONSUME = [&](int pos, const uint4& P0, const uint2& P1, float XV) {
        if (pos < end) {
            float elin = breg;
            float2 e0 = upk(P0.x); elin = fmaf(e0.x, w0, elin);  elin = fmaf(e0.y, w1, elin);
            float2 e1 = upk(P0.y); elin = fmaf(e1.x, w2, elin);  elin = fmaf(e1.y, w3, elin);
            float2 e2 = upk(P0.z); elin = fmaf(e2.x, w4, elin);  elin = fmaf(e2.y, w5, elin);
            float2 e3 = upk(P0.w); elin = fmaf(e3.x, w6, elin);  elin = fmaf(e3.y, w7, elin);
            float2 e4 = upk(P1.x); elin = fmaf(e4.x, w8, elin);  elin = fmaf(e4.y, w9, elin);
            float2 e5 = upk(P1.y); elin = fmaf(e5.x, w10, elin); elin = fmaf(e5.y, w11, elin);
            acc += fmaxf(XV + elin, 0.f);
            int p1 = pos + 1;
            if (p1 == nb) {
                do {
                    out[(size_t)(i0 + np) * 64 + lane] = f2bf(acc + sk);
                    acc = 0.f; ++np;
                    nb = (np < 8) ? __builtin_amdgcn_readlane(rp, np + 1) : 0x7fffffff;
                    sk = (np < 8) ? SKIPLD(np) : 0.f;
                } while (p1 == nb);
            }
        }
    };

    uint4 A0, B0, C0, D0, E0, F0, G0, H0;
    uint2 A1, B1, C1, D1, E1, F1, G1, H1;
    float Ax = 0.f, Bx = 0.f, Cx = 0.f, Dx = 0.f, Ex = 0.f, Fx = 0.f, Gx = 0.f, Hx = 0.f;
    int base = beg;
    LOADE(base + 0, A0, A1, Ax);
    LOADE(base + 1, B0, B1, Bx);
    LOADE(base + 2, C0, C1, Cx);
    LOADE(base + 3, D0, D1, Dx);
    LOADE(base + 4, E0, E1, Ex);
    LOADE(base + 5, F0, F1, Fx);
    LOADE(base + 6, G0, G1, Gx);
    LOADE(base + 7, H0, H1, Hx);
    while (base < end) {
        CONSUME(base + 0, A0, A1, Ax);
        CONSUME(base + 1, B0, B1, Bx);
        LOADE(base + 8, A0, A1, Ax);
        LOADE(base + 9, B0, B1, Bx);
        if (base + 2 >= end) break;
        CONSUME(base + 2, C0, C1, Cx);
        CONSUME(base + 3, D0, D1, Dx);
        LOADE(base + 10, C0, C1, Cx);
        LOADE(base + 11, D0, D1, Dx);
        if (base + 4 >= end) break;
        CONSUME(base + 4, E0, E1, Ex);
        CONSUME(base + 5, F0, F1, Fx);
        LOADE(base + 12, E0, E1, Ex);
        LOADE(base + 13, F0, F1, Fx);
        if (base + 6 >= end) break;
        CONSUME(base + 6, G0, G1, Gx);
        CONSUME(base + 7, H0, H1, Hx);
        LOADE(base + 14, G0, G1, Gx);
        LOADE(base + 15, H0, H1, Hx);
        base += 8;
    }
}

// ---------------------------------------------------------------------------
// Node MLP 1: h = relu( relu(a @ w1a + b1a) @ w1b + b1b ), a = bf16[N][64] in.
// Persistent waves, register-resident weights, per-wave LDS, fp16 output.
#define HSTR1 68
__global__ __launch_bounds__(256, 3) void mlp1(
    const short* __restrict__ ain,
    const short* __restrict__ w1a_t, const float* __restrict__ b1a,
    const short* __restrict__ w1b_t, const float* __restrict__ b1b,
    unsigned short* __restrict__ h) {
    __shared__ float hid[4][16 * HSTR1];
    int lane = threadIdx.x & 63;
    int wv = threadIdx.x >> 6;
    int mrow = lane & 15, q = lane >> 4;
    float* hw = hid[wv];

    bf16x8 wa[4][2], wb[4][2];
    float ba[4], bb[4];
#pragma unroll
    for (int nt = 0; nt < 4; ++nt) {
        int n = nt * 16 + mrow;
        ba[nt] = b1a[n]; bb[nt] = b1b[n];
#pragma unroll
        for (int s = 0; s < 2; ++s) {
            wa[nt][s] = *(const bf16x8*)(w1a_t + n * 64 + s * 32 + q * 8);
            wb[nt][s] = *(const bf16x8*)(w1b_t + n * 64 + s * 32 + q * 8);
        }
    }

    int tile = blockIdx.x * 4 + wv;
    int stride = gridDim.x * 4;
    if (tile >= NTILE) return;
    bf16x8 a0 = *(const bf16x8*)(ain + (size_t)(tile * 16 + mrow) * 64 + q * 8);
    bf16x8 a1 = *(const bf16x8*)(ain + (size_t)(tile * 16 + mrow) * 64 + 32 + q * 8);
    while (true) {
        int nxt = tile + stride;
        bool more = nxt < NTILE;
        bf16x8 na0{}, na1{};
        if (more) {
            na0 = *(const bf16x8*)(ain + (size_t)(nxt * 16 + mrow) * 64 + q * 8);
            na1 = *(const bf16x8*)(ain + (size_t)(nxt * 16 + mrow) * 64 + 32 + q * 8);
        }
        int node0 = tile * 16;
#pragma unroll
        for (int nt = 0; nt < 4; ++nt) {
            f32x4 acc = {ba[nt], ba[nt], ba[nt], ba[nt]};
            acc = __builtin_amdgcn_mfma_f32_16x16x32_bf16(a0, wa[nt][0], acc, 0, 0, 0);
            acc = __builtin_amdgcn_mfma_f32_16x16x32_bf16(a1, wa[nt][1], acc, 0, 0, 0);
            int n = nt * 16 + mrow;
#pragma unroll
            for (int r = 0; r < 4; ++r)
                hw[(q * 4 + r) * HSTR1 + n] = fmaxf(acc[r], 0.f);
        }
        wave_lds_fence();
        bf16x8 af2[2];
#pragma unroll
        for (int s = 0; s < 2; ++s) {
            f32x4 v0 = *(const f32x4*)(hw + mrow * HSTR1 + s * 32 + q * 8);
            f32x4 v1 = *(const f32x4*)(hw + mrow * HSTR1 + s * 32 + q * 8 + 4);
#pragma unroll
            for (int j = 0; j < 4; ++j) { af2[s][j] = f2bf(v0[j]); af2[s][j + 4] = f2bf(v1[j]); }
        }
#pragma unroll
        for (int nt = 0; nt < 4; ++nt) {
            f32x4 acc = {bb[nt], bb[nt], bb[nt], bb[nt]};
            acc = __builtin_amdgcn_mfma_f32_16x16x32_bf16(af2[0], wb[nt][0], acc, 0, 0, 0);
            acc = __builtin_amdgcn_mfma_f32_16x16x32_bf16(af2[1], wb[nt][1], acc, 0, 0, 0);
            int n = nt * 16 + mrow;
#pragma unroll
            for (int r = 0; r < 4; ++r)
                h[(size_t)(node0 + q * 4 + r) * HH + n] = f2h(fmaxf(acc[r], 0.f));
        }
        if (!more) break;
        tile = nxt; a0 = na0; a1 = na1;
        wave_lds_fence();   // order this iter's hw reads vs next iter's writes
    }
}

// ---------------------------------------------------------------------------
// Node MLP 2 + fused mean-pool accumulate: input = bf16[N][64] (h+agg2 fused).
#define HSTR2 132
__global__ __launch_bounds__(256, 2) void mlp2(
    const short* __restrict__ ain,
    const short* __restrict__ w2a_t, const float* __restrict__ b2a,
    const short* __restrict__ w2b_t, const float* __restrict__ b2b,
    const int* __restrict__ batch, float* __restrict__ sums) {
    __shared__ float buf[4][16 * HSTR2];
    int lane = threadIdx.x & 63;
    int wv = threadIdx.x >> 6;
    int mrow = lane & 15, q = lane >> 4;
    float* bw = buf[wv];

    bf16x8 wa[8][2], wb[8][4];
    float ba[8], bb[8];
#pragma unroll
    for (int nt = 0; nt < 8; ++nt) {
        int n = nt * 16 + mrow;
        ba[nt] = b2a[n]; bb[nt] = b2b[n];
#pragma unroll
        for (int s = 0; s < 2; ++s)
            wa[nt][s] = *(const bf16x8*)(w2a_t + n * HH + s * 32 + q * 8);
#pragma unroll
        for (int s = 0; s < 4; ++s)
            wb[nt][s] = *(const bf16x8*)(w2b_t + n * EMB + s * 32 + q * 8);
    }

    int tile = blockIdx.x * 4 + wv;
    int stride = gridDim.x * 4;
    if (tile >= NTILE) return;
    bf16x8 a0 = *(const bf16x8*)(ain + (size_t)(tile * 16 + mrow) * 64 + q * 8);
    bf16x8 a1 = *(const bf16x8*)(ain + (size_t)(tile * 16 + mrow) * 64 + 32 + q * 8);
    int bv = (lane < 16) ? batch[tile * 16 + lane] : 0;
    while (true) {
        int nxt = tile + stride;
        bool more = nxt < NTILE;
        bf16x8 na0{}, na1{};
        int nbv = 0;
        if (more) {
            na0 = *(const bf16x8*)(ain + (size_t)(nxt * 16 + mrow) * 64 + q * 8);
            na1 = *(const bf16x8*)(ain + (size_t)(nxt * 16 + mrow) * 64 + 32 + q * 8);
            nbv = (lane < 16) ? batch[nxt * 16 + lane] : 0;
        }
        // GEMM1: 64 -> 128, relu, to LDS (transpose staging)
#pragma unroll
        for (int nt = 0; nt < 8; ++nt) {
            f32x4 acc = {ba[nt], ba[nt], ba[nt], ba[nt]};
            acc = __builtin_amdgcn_mfma_f32_16x16x32_bf16(a0, wa[nt][0], acc, 0, 0, 0);
            acc = __builtin_amdgcn_mfma_f32_16x16x32_bf16(a1, wa[nt][1], acc, 0, 0, 0);
            int n = nt * 16 + mrow;
#pragma unroll
            for (int r = 0; r < 4; ++r)
                bw[(q * 4 + r) * HSTR2 + n] = fmaxf(acc[r], 0.f);
        }
        wave_lds_fence();
        bf16x8 af2[4];
#pragma unroll
        for (int s = 0; s < 4; ++s) {
            f32x4 v0 = *(const f32x4*)(bw + mrow * HSTR2 + s * 32 + q * 8);
            f32x4 v1 = *(const f32x4*)(bw + mrow * HSTR2 + s * 32 + q * 8 + 4);
#pragma unroll
            for (int j = 0; j < 4; ++j) { af2[s][j] = f2bf(v0[j]); af2[s][j + 4] = f2bf(v1[j]); }
        }
        // GEMM2: 128 -> 128, raw acc to LDS for pooling
#pragma unroll
        for (int nt = 0; nt < 8; ++nt) {
            f32x4 acc = {bb[nt], bb[nt], bb[nt], bb[nt]};
#pragma unroll
            for (int s = 0; s < 4; ++s)
                acc = __builtin_amdgcn_mfma_f32_16x16x32_bf16(af2[s], wb[nt][s], acc, 0, 0, 0);
#pragma unroll
            for (int r = 0; r < 4; ++r)
                bw[(q * 4 + r) * HSTR2 + nt * 16 + mrow] = acc[r];
        }
        wave_lds_fence();
        // fused mean-pool accumulate (batch sorted -> few runs per tile)
#pragma unroll
        for (int cp = 0; cp < 2; ++cp) {
            int col = lane + cp * 64;
            float run = 0.f;
            int bprev = __shfl(bv, 0);
            for (int i = 0; i < 16; ++i) {
                int bg = __shfl(bv, i);
                if (bg != bprev) {
                    atomicAdd(&sums[bprev * EMB + col], run);
                    run = 0.f; bprev = bg;
                }
                run += bw[i * HSTR2 + col];
            }
            atomicAdd(&sums[bprev * EMB + col], run);
        }
        if (!more) break;
        tile = nxt; a0 = na0; a1 = na1; bv = nbv;
        wave_lds_fence();   // order pooling reads vs next iter's GEMM1 writes
    }
}

// ---------------------------------------------------------------------------
__global__ __launch_bounds__(128) void finalize(
    const float* __restrict__ sums, const int* __restrict__ batch,
    float* __restrict__ out) {
    int g = blockIdx.x;
    __shared__ int cnt_s;
    if (threadIdx.x == 0) {
        int lo = 0, hi = NN;
        while (lo < hi) { int mid = (lo + hi) >> 1; if (batch[mid] < g) lo = mid + 1; else hi = mid; }
        int lo2 = lo, hi2 = NN;
        while (lo2 < hi2) { int mid = (lo2 + hi2) >> 1; if (batch[mid] < g + 1) lo2 = mid + 1; else hi2 = mid; }
        cnt_s = lo2 - lo;
    }
    __syncthreads();
    int c = cnt_s > 1 ? cnt_s : 1;
    out[g * EMB + threadIdx.x] = sums[g * EMB + threadIdx.x] / (float)c;
}

// ---------------------------------------------------------------------------
extern "C" void kernel_launch(void* const* d_in, const int* in_sizes, int n_in,
                              void* d_out, int out_size, void* d_ws, size_t ws_size,
                              hipStream_t stream) {
    const float* x    = (const float*)d_in[0];
    const float* ea   = (const float*)d_in[1];
    const int*   ei   = (const int*)d_in[2];
    const int*   batch= (const int*)d_in[3];
    const float* el1w = (const float*)d_in[4];
    const float* el1b = (const float*)d_in[5];
    const float* w1a  = (const float*)d_in[6];
    const float* b1a  = (const float*)d_in[7];
    const float* w1b  = (const float*)d_in[8];
    const float* b1b  = (const float*)d_in[9];
    const float* el2w = (const float*)d_in[10];
    const float* el2b = (const float*)d_in[11];
    const float* w2a  = (const float*)d_in[12];
    const float* b2a  = (const float*)d_in[13];
    const float* w2b  = (const float*)d_in[14];
    const float* b2b  = (const float*)d_in[15];

    char* ws = (char*)d_ws;
    short*          aggout = (short*)ws;                    // [N][64] bf16 (64,000,000 B), both layers
    unsigned short* hbuf16 = (unsigned short*)(ws + 64000000); // [N][64] fp16 (64,000,000 B)
    unsigned int*   csr32  = (unsigned int*)(ws + 128000000);  // [E] 32B rows (64,000,000 B)
    int*   rowptr = (int*)(ws + 192000000);                 // N+1
    int*   cursor = (int*)(ws + 194000064);                 // N
    int*   deg    = (int*)(ws + 196000064);                 // N
    int*   bsum   = (int*)(ws + 198000064);                 // NBLK
    int*   boff   = (int*)(ws + 198000576);                 // NBLK
    float* sums   = (float*)(ws + 198001088);               // G*128 f32
    short* wts    = (short*)(ws + 206389696);               // 32768 shorts
    short* w1a_t = wts;
    short* w1b_t = wts + 4096;
    short* w2a_t = wts + 8192;
    short* w2b_t = wts + 16384;

    hipMemsetAsync(deg, 0, (size_t)NN * 4, stream);
    hipMemsetAsync(sums, 0, (size_t)GG * EMB * 4, stream);

    prep_weights<<<128, 256, 0, stream>>>(w1a, w1b, w2a, w2b, wts);
    // CSR build (+ fp16 attr pack + src fused into 32B rows)
    hist_kernel<<<(EE + 255) / 256, 256, 0, stream>>>(ei, deg);
    scan_reduce<<<NBLK, 256, 0, stream>>>(deg, bsum);
    scan_mid<<<1, 128, 0, stream>>>(bsum, boff, rowptr);
    scan_final<<<NBLK, 256, 0, stream>>>(deg, boff, rowptr, cursor);
    scatter_kernel<<<(EE + 255) / 256, 256, 0, stream>>>(ei, ea, cursor, csr32);
    // Layer 1
    agg_gather<ND><<<NN / 32, 256, 0, stream>>>(x, nullptr, csr32, el1w, el1b, rowptr, aggout);
    mlp1<<<1024, 256, 0, stream>>>(aggout, w1a_t, b1a, w1b_t, b1b, hbuf16);
    // Layer 2
    agg_gather<HH><<<NN / 32, 256, 0, stream>>>(nullptr, hbuf16, csr32, el2w, el2b, rowptr, aggout);
    mlp2<<<7813, 256, 0, stream>>>(aggout, w2a_t, b2a, w2b_t, b2b, batch, sums);
    finalize<<<GG, 128, 0, stream>>>(sums, batch, (float*)d_out);
}

// Round 4
// 823.242 us; speedup vs baseline: 1.2819x; 1.2819x over previous
//
#include <hip/hip_runtime.h>
#include <hip/hip_bf16.h>

#define NN 500000
#define EE 2000000
#define GG 16384
#define ND 44
#define ED 12
#define HH 64
#define EMB 128
#define NBLK 123          // ceil(NN / 4096) scan blocks
#define NTILE (NN / 16)   // 31250, exact

typedef __attribute__((ext_vector_type(8))) short bf16x8;
typedef __attribute__((ext_vector_type(4))) float f32x4;

// fp32 -> bf16 round-to-nearest-even, bit pattern as short
__device__ inline short f2bf(float v) {
    unsigned int x = __builtin_bit_cast(unsigned int, v);
    x += 0x7FFFu + ((x >> 16) & 1u);
    return (short)(x >> 16);
}
// fp32 <-> fp16 (RNE, v_cvt_f16_f32 / v_cvt_f32_f16)
__device__ inline unsigned short f2h(float v) {
    return __builtin_bit_cast(unsigned short, (_Float16)v);
}
__device__ inline float h2f(unsigned short s) {
    return (float)__builtin_bit_cast(_Float16, s);
}
__device__ inline unsigned pkh(float a, float b) {
    return (unsigned)f2h(a) | ((unsigned)f2h(b) << 16);
}
__device__ inline float2 upk(unsigned u) {
    return make_float2((float)__builtin_bit_cast(_Float16, (unsigned short)(u & 0xffffu)),
                       (float)__builtin_bit_cast(_Float16, (unsigned short)(u >> 16)));
}

// Wave-local LDS ordering fence (per-wave LDS buffers; does NOT drain vmcnt).
__device__ inline void wave_lds_fence() {
    asm volatile("s_waitcnt lgkmcnt(0)" ::: "memory");
    __builtin_amdgcn_sched_barrier(0);
}

// ---------------------------------------------------------------------------
// Weight prep: transpose to [n][k] layout, cast to bf16, zero-pad K of w1a to 64
__global__ __launch_bounds__(256) void prep_weights(
    const float* __restrict__ w1a, const float* __restrict__ w1b,
    const float* __restrict__ w2a, const float* __restrict__ w2b,
    short* __restrict__ o) {
    int t = blockIdx.x * 256 + threadIdx.x;
    if (t < 4096) {
        int n = t >> 6, k = t & 63;
        o[t] = f2bf(k < ND ? w1a[k * HH + n] : 0.f);
    } else if (t < 8192) {
        int u = t - 4096; int n = u >> 6, k = u & 63;
        o[t] = f2bf(w1b[k * HH + n]);
    } else if (t < 16384) {
        int u = t - 8192; int n = u >> 6, k = u & 63;
        o[t] = f2bf(w2a[k * EMB + n]);
    } else if (t < 32768) {
        int u = t - 16384; int n = u >> 7, k = u & 127;
        o[t] = f2bf(w2b[k * EMB + n]);
    }
}

// ---------------------------------------------------------------------------
// CSR build: histogram of dst, exclusive scan, scatter by dst.
__global__ __launch_bounds__(256) void hist_kernel(const int* __restrict__ ei,
                                                   int* __restrict__ deg) {
    int e = blockIdx.x * 256 + threadIdx.x;
    if (e < EE) atomicAdd(&deg[ei[EE + e]], 1);
}

__global__ __launch_bounds__(256) void scan_reduce(const int* __restrict__ deg,
                                                   int* __restrict__ bsum) {
    int b = blockIdx.x, t = threadIdx.x;
    int base = b * 4096;
    int s = 0;
    for (int i = t; i < 4096; i += 256) {
        int g = base + i;
        if (g < NN) s += deg[g];
    }
#pragma unroll
    for (int off = 32; off; off >>= 1) s += __shfl_xor(s, off);
    __shared__ int ws[4];
    if ((t & 63) == 0) ws[t >> 6] = s;
    __syncthreads();
    if (t == 0) bsum[b] = ws[0] + ws[1] + ws[2] + ws[3];
}

__global__ __launch_bounds__(128) void scan_mid(const int* __restrict__ bsum,
                                                int* __restrict__ boff,
                                                int* __restrict__ rowptr) {
    int t = threadIdx.x;
    int v = (t < NBLK) ? bsum[t] : 0;
    int x = v;
#pragma unroll
    for (int off = 1; off < 64; off <<= 1) {
        int y = __shfl_up(x, off);
        if ((t & 63) >= off) x += y;
    }
    __shared__ int wt[2];
    if ((t & 63) == 63) wt[t >> 6] = x;
    __syncthreads();
    int xx = x + ((t >= 64) ? wt[0] : 0);
    if (t < NBLK) boff[t] = xx - v;
    if (t == 127) rowptr[NN] = xx;
}

__global__ __launch_bounds__(256) void scan_final(const int* __restrict__ deg,
                                                  const int* __restrict__ boff,
                                                  int* __restrict__ rowptr,
                                                  int* __restrict__ cursor) {
    int b = blockIdx.x, t = threadIdx.x;
    int base = b * 4096 + t * 16;
    int loc[16];
    int s = 0;
#pragma unroll
    for (int j = 0; j < 16; ++j) {
        int g = base + j;
        loc[j] = (g < NN) ? deg[g] : 0;
        s += loc[j];
    }
    int xinc = s;
#pragma unroll
    for (int off = 1; off < 64; off <<= 1) {
        int y = __shfl_up(xinc, off);
        if ((t & 63) >= off) xinc += y;
    }
    __shared__ int wt[4];
    if ((t & 63) == 63) wt[t >> 6] = xinc;
    __syncthreads();
    int wv = t >> 6, woff = 0;
#pragma unroll
    for (int k = 0; k < 4; ++k)
        if (k < wv) woff += wt[k];
    int run = boff[b] + woff + (xinc - s);
#pragma unroll
    for (int j = 0; j < 16; ++j) {
        int g = base + j;
        if (g < NN) { rowptr[g] = run; cursor[g] = run; }
        run += loc[j];
    }
}

// Scatter: build 32B CSR rows: [12 x fp16 edge-attr (24B) | src int (4B) | pad].
// 32B-aligned writes never straddle a 64B line -> no partial-line RMW.
__global__ __launch_bounds__(256) void scatter_kernel(const int* __restrict__ ei,
                                                      const float* __restrict__ ea,
                                                      int* __restrict__ cursor,
                                                      unsigned int* __restrict__ csr) {
    int e = blockIdx.x * 256 + threadIdx.x;
    if (e < EE) {
        int dst = ei[EE + e];
        const float4* s = (const float4*)(ea + (size_t)e * ED);
        float4 a0 = s[0], a1 = s[1], a2 = s[2];
        uint4 P0, P1;
        P0.x = pkh(a0.x, a0.y); P0.y = pkh(a0.z, a0.w);
        P0.z = pkh(a1.x, a1.y); P0.w = pkh(a1.z, a1.w);
        P1.x = pkh(a2.x, a2.y); P1.y = pkh(a2.z, a2.w);
        P1.z = (unsigned)ei[e];   // src at word 6
        P1.w = 0u;
        int pos = atomicAdd(&cursor[dst], 1);
        uint4* d = (uint4*)(csr + (size_t)pos * 8);
        d[0] = P0; d[1] = P1;
    }
}

// ---------------------------------------------------------------------------
// Gather aggregation, 8 nodes/wave, fused skip-add + bf16 output:
//   out16[i][0:64] = bf16( xf[i] + sum_{e: dst=i} relu(xf[src] + ea@W + b) )
template <int D>
__global__ __launch_bounds__(256) void agg_gather(
    const float* __restrict__ xf32, const unsigned short* __restrict__ xf16,
    const unsigned int* __restrict__ cea,
    const float* __restrict__ ew, const float* __restrict__ eb,
    const int* __restrict__ rowptr,
    short* __restrict__ out) {
    int lane = threadIdx.x & 63;
    int wv = threadIdx.x >> 6;
    int i0 = (blockIdx.x * 4 + wv) * 8;
    if (i0 >= NN) return;
    float w0, w1, w2, w3, w4, w5, w6, w7, w8, w9, w10, w11, breg;
    if (D == 64 || lane < D) {
        w0 = ew[0 * D + lane];  w1 = ew[1 * D + lane];  w2 = ew[2 * D + lane];
        w3 = ew[3 * D + lane];  w4 = ew[4 * D + lane];  w5 = ew[5 * D + lane];
        w6 = ew[6 * D + lane];  w7 = ew[7 * D + lane];  w8 = ew[8 * D + lane];
        w9 = ew[9 * D + lane];  w10 = ew[10 * D + lane]; w11 = ew[11 * D + lane];
        breg = eb[lane];
    } else {
        w0=w1=w2=w3=w4=w5=w6=w7=w8=w9=w10=w11=0.f; breg = 0.f;
    }
    int rp = (lane <= 8) ? rowptr[i0 + lane] : 0;
    int beg = __builtin_amdgcn_readfirstlane(__builtin_amdgcn_readlane(rp, 0));
    int end = __builtin_amdgcn_readfirstlane(__builtin_amdgcn_readlane(rp, 8));
    int s0 = 0, s1 = 0;
    if (beg + lane < end) s0 = (int)cea[(size_t)(beg + lane) * 8 + 6];
    if (beg + 64 + lane < end) s1 = (int)cea[(size_t)(beg + 64 + lane) * 8 + 6];

    auto SKIPLD = [&](int j) -> float {
        if (D == HH) return h2f(xf16[(size_t)(i0 + j) * HH + lane]);
        return (lane < D) ? xf32[(size_t)(i0 + j) * ND + lane] : 0.f;
    };

    float acc = 0.f;
    int np = 0;
    int nb = __builtin_amdgcn_readlane(rp, 1);
    float sk = SKIPLD(0);
    while (np < 8 && nb == beg) {
        out[(size_t)(i0 + np) * 64 + lane] = f2bf(sk);   // acc == 0
        ++np;
        nb = (np < 8) ? __builtin_amdgcn_readlane(rp, np + 1) : 0x7fffffff;
        sk = (np < 8) ? SKIPLD(np) : 0.f;
    }

    auto LOADE = [&](int pos, uint4& P0, uint2& P1, float& XV) {
        if (pos < end) {
            int off = pos - beg;
            int src;
            if (off < 64)       src = __builtin_amdgcn_readlane(s0, off);
            else if (off < 128) src = __builtin_amdgcn_readlane(s1, off - 64);
            else                src = __builtin_amdgcn_readfirstlane((int)cea[(size_t)pos * 8 + 6]);
            P0 = *(const uint4*)(cea + (size_t)pos * 8);
            P1 = *(const uint2*)(cea + (size_t)pos * 8 + 4);
            if (D == HH) XV = h2f(xf16[(size_t)src * HH + lane]);
            else         XV = (lane < D) ? xf32[(size_t)src * ND + lane] : 0.f;
        }
    };
    auto CONSUME = [&](int pos, const uint4& P0, const uint2& P1, float XV) {
        if (pos < end) {
            float elin = breg;
            float2 e0 = upk(P0.x); elin = fmaf(e0.x, w0, elin);  elin = fmaf(e0.y, w1, elin);
            float2 e1 = upk(P0.y); elin = fmaf(e1.x, w2, elin);  elin = fmaf(e1.y, w3, elin);
            float2 e2 = upk(P0.z); elin = fmaf(e2.x, w4, elin);  elin = fmaf(e2.y, w5, elin);
            float2 e3 = upk(P0.w); elin = fmaf(e3.x, w6, elin);  elin = fmaf(e3.y, w7, elin);
            float2 e4 = upk(P1.x); elin = fmaf(e4.x, w8, elin);  elin = fmaf(e4.y, w9, elin);
            float2 e5 = upk(P1.y); elin = fmaf(e5.x, w10, elin); elin = fmaf(e5.y, w11, elin);
            acc += fmaxf(XV + elin, 0.f);
            int p1 = pos + 1;
            if (p1 == nb) {
                do {
                    out[(size_t)(i0 + np) * 64 + lane] = f2bf(acc + sk);
                    acc = 0.f; ++np;
                    nb = (np < 8) ? __builtin_amdgcn_readlane(rp, np + 1) : 0x7fffffff;
                    sk = (np < 8) ? SKIPLD(np) : 0.f;
                } while (p1 == nb);
            }
        }
    };

    uint4 A0, B0, C0, D0, E0, F0, G0, H0;
    uint2 A1, B1, C1, D1, E1, F1, G1, H1;
    float Ax = 0.f, Bx = 0.f, Cx = 0.f, Dx = 0.f, Ex = 0.f, Fx = 0.f, Gx = 0.f, Hx = 0.f;
    int base = beg;
    LOADE(base + 0, A0, A1, Ax);
    LOADE(base + 1, B0, B1, Bx);
    LOADE(base + 2, C0, C1, Cx);
    LOADE(base + 3, D0, D1, Dx);
    LOADE(base + 4, E0, E1, Ex);
    LOADE(base + 5, F0, F1, Fx);
    LOADE(base + 6, G0, G1, Gx);
    LOADE(base + 7, H0, H1, Hx);
    while (base < end) {
        CONSUME(base + 0, A0, A1, Ax);
        CONSUME(base + 1, B0, B1, Bx);
        LOADE(base + 8, A0, A1, Ax);
        LOADE(base + 9, B0, B1, Bx);
        if (base + 2 >= end) break;
        CONSUME(base + 2, C0, C1, Cx);
        CONSUME(base + 3, D0, D1, Dx);
        LOADE(base + 10, C0, C1, Cx);
        LOADE(base + 11, D0, D1, Dx);
        if (base + 4 >= end) break;
        CONSUME(base + 4, E0, E1, Ex);
        CONSUME(base + 5, F0, F1, Fx);
        LOADE(base + 12, E0, E1, Ex);
        LOADE(base + 13, F0, F1, Fx);
        if (base + 6 >= end) break;
        CONSUME(base + 6, G0, G1, Gx);
        CONSUME(base + 7, H0, H1, Hx);
        LOADE(base + 14, G0, G1, Gx);
        LOADE(base + 15, H0, H1, Hx);
        base += 8;
    }
}

// ---------------------------------------------------------------------------
// Node MLP 1: h = relu( relu(a @ w1a + b1a) @ w1b + b1b ), a = bf16[N][64] in.
// Persistent waves, register-resident weights (64 VGPR total), per-wave LDS.
#define HSTR1 68
__global__ __launch_bounds__(256, 3) void mlp1(
    const short* __restrict__ ain,
    const short* __restrict__ w1a_t, const float* __restrict__ b1a,
    const short* __restrict__ w1b_t, const float* __restrict__ b1b,
    unsigned short* __restrict__ h) {
    __shared__ float hid[4][16 * HSTR1];
    int lane = threadIdx.x & 63;
    int wv = threadIdx.x >> 6;
    int mrow = lane & 15, q = lane >> 4;
    float* hw = hid[wv];

    bf16x8 wa[4][2], wb[4][2];
    float ba[4], bb[4];
#pragma unroll
    for (int nt = 0; nt < 4; ++nt) {
        int n = nt * 16 + mrow;
        ba[nt] = b1a[n]; bb[nt] = b1b[n];
#pragma unroll
        for (int s = 0; s < 2; ++s) {
            wa[nt][s] = *(const bf16x8*)(w1a_t + n * 64 + s * 32 + q * 8);
            wb[nt][s] = *(const bf16x8*)(w1b_t + n * 64 + s * 32 + q * 8);
        }
    }

    int tile = blockIdx.x * 4 + wv;
    int stride = gridDim.x * 4;
    if (tile >= NTILE) return;
    bf16x8 a0 = *(const bf16x8*)(ain + (size_t)(tile * 16 + mrow) * 64 + q * 8);
    bf16x8 a1 = *(const bf16x8*)(ain + (size_t)(tile * 16 + mrow) * 64 + 32 + q * 8);
    while (true) {
        int nxt = tile + stride;
        bool more = nxt < NTILE;
        bf16x8 na0{}, na1{};
        if (more) {
            na0 = *(const bf16x8*)(ain + (size_t)(nxt * 16 + mrow) * 64 + q * 8);
            na1 = *(const bf16x8*)(ain + (size_t)(nxt * 16 + mrow) * 64 + 32 + q * 8);
        }
        int node0 = tile * 16;
#pragma unroll
        for (int nt = 0; nt < 4; ++nt) {
            f32x4 acc = {ba[nt], ba[nt], ba[nt], ba[nt]};
            acc = __builtin_amdgcn_mfma_f32_16x16x32_bf16(a0, wa[nt][0], acc, 0, 0, 0);
            acc = __builtin_amdgcn_mfma_f32_16x16x32_bf16(a1, wa[nt][1], acc, 0, 0, 0);
            int n = nt * 16 + mrow;
#pragma unroll
            for (int r = 0; r < 4; ++r)
                hw[(q * 4 + r) * HSTR1 + n] = fmaxf(acc[r], 0.f);
        }
        wave_lds_fence();
        bf16x8 af2[2];
#pragma unroll
        for (int s = 0; s < 2; ++s) {
            f32x4 v0 = *(const f32x4*)(hw + mrow * HSTR1 + s * 32 + q * 8);
            f32x4 v1 = *(const f32x4*)(hw + mrow * HSTR1 + s * 32 + q * 8 + 4);
#pragma unroll
            for (int j = 0; j < 4; ++j) { af2[s][j] = f2bf(v0[j]); af2[s][j + 4] = f2bf(v1[j]); }
        }
#pragma unroll
        for (int nt = 0; nt < 4; ++nt) {
            f32x4 acc = {bb[nt], bb[nt], bb[nt], bb[nt]};
            acc = __builtin_amdgcn_mfma_f32_16x16x32_bf16(af2[0], wb[nt][0], acc, 0, 0, 0);
            acc = __builtin_amdgcn_mfma_f32_16x16x32_bf16(af2[1], wb[nt][1], acc, 0, 0, 0);
            int n = nt * 16 + mrow;
#pragma unroll
            for (int r = 0; r < 4; ++r)
                h[(size_t)(node0 + q * 4 + r) * HH + n] = f2h(fmaxf(acc[r], 0.f));
        }
        if (!more) break;
        tile = nxt; a0 = na0; a1 = na1;
        wave_lds_fence();   // order this iter's hw reads vs next iter's writes
    }
}

// ---------------------------------------------------------------------------
// Node MLP 2 + fused mean-pool accumulate: input = bf16[N][64] (h+agg2 fused).
// Persistent waves (grid 512 = 2 blocks/CU). wa (GEMM1) register-resident
// (64 VGPR); w2b (GEMM2, 32KB) staged ONCE per block into LDS with padded
// stride 136 shorts (+16B) so fragment ds_read_b128 is ~2-way bank-aliased
// (free) instead of 16-way. This removes round-3's VGPR spill (192-reg weight
// set -> scratch, 507MB WRITE_SIZE).
#define HSTR2 132
#define WLSTR 136
__global__ __launch_bounds__(256, 2) void mlp2(
    const short* __restrict__ ain,
    const short* __restrict__ w2a_t, const float* __restrict__ b2a,
    const short* __restrict__ w2b_t, const float* __restrict__ b2b,
    const int* __restrict__ batch, float* __restrict__ sums) {
    __shared__ float buf[4][16 * HSTR2];
    __shared__ short wlds[EMB * WLSTR];
    int lane = threadIdx.x & 63;
    int wv = threadIdx.x >> 6;
    int mrow = lane & 15, q = lane >> 4;
    float* bw = buf[wv];

    // stage w2b -> LDS once per block (16384 shorts)
    for (int idx = threadIdx.x * 8; idx < EMB * EMB; idx += 2048) {
        int n = idx >> 7, k = idx & 127;
        *(bf16x8*)(wlds + n * WLSTR + k) = *(const bf16x8*)(w2b_t + idx);
    }

    bf16x8 wa[8][2];
    float ba[8], bb[8];
#pragma unroll
    for (int nt = 0; nt < 8; ++nt) {
        int n = nt * 16 + mrow;
        ba[nt] = b2a[n]; bb[nt] = b2b[n];
#pragma unroll
        for (int s = 0; s < 2; ++s)
            wa[nt][s] = *(const bf16x8*)(w2a_t + n * HH + s * 32 + q * 8);
    }
    __syncthreads();   // once: wlds visible to all waves

    int tile = blockIdx.x * 4 + wv;
    int stride = gridDim.x * 4;
    if (tile >= NTILE) return;
    bf16x8 a0 = *(const bf16x8*)(ain + (size_t)(tile * 16 + mrow) * 64 + q * 8);
    bf16x8 a1 = *(const bf16x8*)(ain + (size_t)(tile * 16 + mrow) * 64 + 32 + q * 8);
    int bv = (lane < 16) ? batch[tile * 16 + lane] : 0;
    while (true) {
        int nxt = tile + stride;
        bool more = nxt < NTILE;
        bf16x8 na0{}, na1{};
        int nbv = 0;
        if (more) {
            na0 = *(const bf16x8*)(ain + (size_t)(nxt * 16 + mrow) * 64 + q * 8);
            na1 = *(const bf16x8*)(ain + (size_t)(nxt * 16 + mrow) * 64 + 32 + q * 8);
            nbv = (lane < 16) ? batch[nxt * 16 + lane] : 0;
        }
        // GEMM1: 64 -> 128, relu, to LDS (transpose staging)
#pragma unroll
        for (int nt = 0; nt < 8; ++nt) {
            f32x4 acc = {ba[nt], ba[nt], ba[nt], ba[nt]};
            acc = __builtin_amdgcn_mfma_f32_16x16x32_bf16(a0, wa[nt][0], acc, 0, 0, 0);
            acc = __builtin_amdgcn_mfma_f32_16x16x32_bf16(a1, wa[nt][1], acc, 0, 0, 0);
            int n = nt * 16 + mrow;
#pragma unroll
            for (int r = 0; r < 4; ++r)
                bw[(q * 4 + r) * HSTR2 + n] = fmaxf(acc[r], 0.f);
        }
        wave_lds_fence();
        bf16x8 af2[4];
#pragma unroll
        for (int s = 0; s < 4; ++s) {
            f32x4 v0 = *(const f32x4*)(bw + mrow * HSTR2 + s * 32 + q * 8);
            f32x4 v1 = *(const f32x4*)(bw + mrow * HSTR2 + s * 32 + q * 8 + 4);
#pragma unroll
            for (int j = 0; j < 4; ++j) { af2[s][j] = f2bf(v0[j]); af2[s][j + 4] = f2bf(v1[j]); }
        }
        // GEMM2: 128 -> 128, B-fragments streamed from LDS, raw acc to LDS
#pragma unroll
        for (int nt = 0; nt < 8; ++nt) {
            f32x4 acc = {bb[nt], bb[nt], bb[nt], bb[nt]};
#pragma unroll
            for (int s = 0; s < 4; ++s) {
                bf16x8 bfrag = *(const bf16x8*)(wlds + (nt * 16 + mrow) * WLSTR + s * 32 + q * 8);
                acc = __builtin_amdgcn_mfma_f32_16x16x32_bf16(af2[s], bfrag, acc, 0, 0, 0);
            }
#pragma unroll
            for (int r = 0; r < 4; ++r)
                bw[(q * 4 + r) * HSTR2 + nt * 16 + mrow] = acc[r];
        }
        wave_lds_fence();
        // fused mean-pool accumulate (batch sorted -> few runs per tile)
#pragma unroll
        for (int cp = 0; cp < 2; ++cp) {
            int col = lane + cp * 64;
            float run = 0.f;
            int bprev = __shfl(bv, 0);
            for (int i = 0; i < 16; ++i) {
                int bg = __shfl(bv, i);
                if (bg != bprev) {
                    atomicAdd(&sums[bprev * EMB + col], run);
                    run = 0.f; bprev = bg;
                }
                run += bw[i * HSTR2 + col];
            }
            atomicAdd(&sums[bprev * EMB + col], run);
        }
        if (!more) break;
        tile = nxt; a0 = na0; a1 = na1; bv = nbv;
        wave_lds_fence();   // order pooling reads vs next iter's GEMM1 writes
    }
}

// ---------------------------------------------------------------------------
__global__ __launch_bounds__(128) void finalize(
    const float* __restrict__ sums, const int* __restrict__ batch,
    float* __restrict__ out) {
    int g = blockIdx.x;
    __shared__ int cnt_s;
    if (threadIdx.x == 0) {
        int lo = 0, hi = NN;
        while (lo < hi) { int mid = (lo + hi) >> 1; if (batch[mid] < g) lo = mid + 1; else hi = mid; }
        int lo2 = lo, hi2 = NN;
        while (lo2 < hi2) { int mid = (lo2 + hi2) >> 1; if (batch[mid] < g + 1) lo2 = mid + 1; else hi2 = mid; }
        cnt_s = lo2 - lo;
    }
    __syncthreads();
    int c = cnt_s > 1 ? cnt_s : 1;
    out[g * EMB + threadIdx.x] = sums[g * EMB + threadIdx.x] / (float)c;
}

// ---------------------------------------------------------------------------
extern "C" void kernel_launch(void* const* d_in, const int* in_sizes, int n_in,
                              void* d_out, int out_size, void* d_ws, size_t ws_size,
                              hipStream_t stream) {
    const float* x    = (const float*)d_in[0];
    const float* ea   = (const float*)d_in[1];
    const int*   ei   = (const int*)d_in[2];
    const int*   batch= (const int*)d_in[3];
    const float* el1w = (const float*)d_in[4];
    const float* el1b = (const float*)d_in[5];
    const float* w1a  = (const float*)d_in[6];
    const float* b1a  = (const float*)d_in[7];
    const float* w1b  = (const float*)d_in[8];
    const float* b1b  = (const float*)d_in[9];
    const float* el2w = (const float*)d_in[10];
    const float* el2b = (const float*)d_in[11];
    const float* w2a  = (const float*)d_in[12];
    const float* b2a  = (const float*)d_in[13];
    const float* w2b  = (const float*)d_in[14];
    const float* b2b  = (const float*)d_in[15];

    char* ws = (char*)d_ws;
    short*          aggout = (short*)ws;                    // [N][64] bf16 (64,000,000 B), both layers
    unsigned short* hbuf16 = (unsigned short*)(ws + 64000000); // [N][64] fp16 (64,000,000 B)
    unsigned int*   csr32  = (unsigned int*)(ws + 128000000);  // [E] 32B rows (64,000,000 B)
    int*   rowptr = (int*)(ws + 192000000);                 // N+1
    int*   cursor = (int*)(ws + 194000064);                 // N
    int*   deg    = (int*)(ws + 196000064);                 // N
    int*   bsum   = (int*)(ws + 198000064);                 // NBLK
    int*   boff   = (int*)(ws + 198000576);                 // NBLK
    float* sums   = (float*)(ws + 198001088);               // G*128 f32
    short* wts    = (short*)(ws + 206389696);               // 32768 shorts
    short* w1a_t = wts;
    short* w1b_t = wts + 4096;
    short* w2a_t = wts + 8192;
    short* w2b_t = wts + 16384;

    hipMemsetAsync(deg, 0, (size_t)NN * 4, stream);
    hipMemsetAsync(sums, 0, (size_t)GG * EMB * 4, stream);

    prep_weights<<<128, 256, 0, stream>>>(w1a, w1b, w2a, w2b, wts);
    // CSR build (+ fp16 attr pack + src fused into 32B rows)
    hist_kernel<<<(EE + 255) / 256, 256, 0, stream>>>(ei, deg);
    scan_reduce<<<NBLK, 256, 0, stream>>>(deg, bsum);
    scan_mid<<<1, 128, 0, stream>>>(bsum, boff, rowptr);
    scan_final<<<NBLK, 256, 0, stream>>>(deg, boff, rowptr, cursor);
    scatter_kernel<<<(EE + 255) / 256, 256, 0, stream>>>(ei, ea, cursor, csr32);
    // Layer 1
    agg_gather<ND><<<NN / 32, 256, 0, stream>>>(x, nullptr, csr32, el1w, el1b, rowptr, aggout);
    mlp1<<<1024, 256, 0, stream>>>(aggout, w1a_t, b1a, w1b_t, b1b, hbuf16);
    // Layer 2
    agg_gather<HH><<<NN / 32, 256, 0, stream>>>(nullptr, hbuf16, csr32, el2w, el2b, rowptr, aggout);
    mlp2<<<512, 256, 0, stream>>>(aggout, w2a_t, b2a, w2b_t, b2b, batch, sums);
    finalize<<<GG, 128, 0, stream>>>(sums, batch, (float*)d_out);
}

// Round 5
// 775.107 us; speedup vs baseline: 1.3615x; 1.0621x over previous
//
#include <hip/hip_runtime.h>
#include <hip/hip_bf16.h>

#define NN 500000
#define EE 2000000
#define GG 16384
#define ND 44
#define ED 12
#define HH 64
#define EMB 128
#define NBLK 123          // ceil(NN / 4096) scan blocks
#define NTILE (NN / 16)   // 31250, exact

typedef __attribute__((ext_vector_type(8))) short bf16x8;
typedef __attribute__((ext_vector_type(4))) float f32x4;

// fp32 -> bf16 round-to-nearest-even, bit pattern as short
__device__ inline short f2bf(float v) {
    unsigned int x = __builtin_bit_cast(unsigned int, v);
    x += 0x7FFFu + ((x >> 16) & 1u);
    return (short)(x >> 16);
}
// fp32 <-> fp16 (RNE, v_cvt_f16_f32 / v_cvt_f32_f16)
__device__ inline unsigned short f2h(float v) {
    return __builtin_bit_cast(unsigned short, (_Float16)v);
}
__device__ inline float h2f(unsigned short s) {
    return (float)__builtin_bit_cast(_Float16, s);
}
__device__ inline unsigned pkh(float a, float b) {
    return (unsigned)f2h(a) | ((unsigned)f2h(b) << 16);
}
__device__ inline float2 upk(unsigned u) {
    return make_float2((float)__builtin_bit_cast(_Float16, (unsigned short)(u & 0xffffu)),
                       (float)__builtin_bit_cast(_Float16, (unsigned short)(u >> 16)));
}

// Wave-local LDS ordering fence (per-wave LDS buffers; does NOT drain vmcnt).
__device__ inline void wave_lds_fence() {
    asm volatile("s_waitcnt lgkmcnt(0)" ::: "memory");
    __builtin_amdgcn_sched_barrier(0);
}

// ---------------------------------------------------------------------------
// Weight prep: transpose to [n][k] layout, cast to bf16, zero-pad K of w1a to 64
__global__ __launch_bounds__(256) void prep_weights(
    const float* __restrict__ w1a, const float* __restrict__ w1b,
    const float* __restrict__ w2a, const float* __restrict__ w2b,
    short* __restrict__ o) {
    int t = blockIdx.x * 256 + threadIdx.x;
    if (t < 4096) {
        int n = t >> 6, k = t & 63;
        o[t] = f2bf(k < ND ? w1a[k * HH + n] : 0.f);
    } else if (t < 8192) {
        int u = t - 4096; int n = u >> 6, k = u & 63;
        o[t] = f2bf(w1b[k * HH + n]);
    } else if (t < 16384) {
        int u = t - 8192; int n = u >> 6, k = u & 63;
        o[t] = f2bf(w2a[k * EMB + n]);
    } else if (t < 32768) {
        int u = t - 16384; int n = u >> 7, k = u & 127;
        o[t] = f2bf(w2b[k * EMB + n]);
    }
}

// ---------------------------------------------------------------------------
// CSR build: histogram of dst, exclusive scan, scatter by dst.
__global__ __launch_bounds__(256) void hist_kernel(const int* __restrict__ ei,
                                                   int* __restrict__ deg) {
    int e = blockIdx.x * 256 + threadIdx.x;
    if (e < EE) atomicAdd(&deg[ei[EE + e]], 1);
}

__global__ __launch_bounds__(256) void scan_reduce(const int* __restrict__ deg,
                                                   int* __restrict__ bsum) {
    int b = blockIdx.x, t = threadIdx.x;
    int base = b * 4096;
    int s = 0;
    for (int i = t; i < 4096; i += 256) {
        int g = base + i;
        if (g < NN) s += deg[g];
    }
#pragma unroll
    for (int off = 32; off; off >>= 1) s += __shfl_xor(s, off);
    __shared__ int ws[4];
    if ((t & 63) == 0) ws[t >> 6] = s;
    __syncthreads();
    if (t == 0) bsum[b] = ws[0] + ws[1] + ws[2] + ws[3];
}

__global__ __launch_bounds__(128) void scan_mid(const int* __restrict__ bsum,
                                                int* __restrict__ boff,
                                                int* __restrict__ rowptr) {
    int t = threadIdx.x;
    int v = (t < NBLK) ? bsum[t] : 0;
    int x = v;
#pragma unroll
    for (int off = 1; off < 64; off <<= 1) {
        int y = __shfl_up(x, off);
        if ((t & 63) >= off) x += y;
    }
    __shared__ int wt[2];
    if ((t & 63) == 63) wt[t >> 6] = x;
    __syncthreads();
    int xx = x + ((t >= 64) ? wt[0] : 0);
    if (t < NBLK) boff[t] = xx - v;
    if (t == 127) rowptr[NN] = xx;
}

__global__ __launch_bounds__(256) void scan_final(const int* __restrict__ deg,
                                                  const int* __restrict__ boff,
                                                  int* __restrict__ rowptr,
                                                  int* __restrict__ cursor) {
    int b = blockIdx.x, t = threadIdx.x;
    int base = b * 4096 + t * 16;
    int loc[16];
    int s = 0;
#pragma unroll
    for (int j = 0; j < 16; ++j) {
        int g = base + j;
        loc[j] = (g < NN) ? deg[g] : 0;
        s += loc[j];
    }
    int xinc = s;
#pragma unroll
    for (int off = 1; off < 64; off <<= 1) {
        int y = __shfl_up(xinc, off);
        if ((t & 63) >= off) xinc += y;
    }
    __shared__ int wt[4];
    if ((t & 63) == 63) wt[t >> 6] = xinc;
    __syncthreads();
    int wv = t >> 6, woff = 0;
#pragma unroll
    for (int k = 0; k < 4; ++k)
        if (k < wv) woff += wt[k];
    int run = boff[b] + woff + (xinc - s);
#pragma unroll
    for (int j = 0; j < 16; ++j) {
        int g = base + j;
        if (g < NN) { rowptr[g] = run; cursor[g] = run; }
        run += loc[j];
    }
}

// Scatter: build 32B CSR rows: [12 x fp16 edge-attr (24B) | src int (4B) | pad].
// 32B-aligned writes never straddle a 64B line -> no partial-line RMW.
__global__ __launch_bounds__(256) void scatter_kernel(const int* __restrict__ ei,
                                                      const float* __restrict__ ea,
                                                      int* __restrict__ cursor,
                                                      unsigned int* __restrict__ csr) {
    int e = blockIdx.x * 256 + threadIdx.x;
    if (e < EE) {
        int dst = ei[EE + e];
        const float4* s = (const float4*)(ea + (size_t)e * ED);
        float4 a0 = s[0], a1 = s[1], a2 = s[2];
        uint4 P0, P1;
        P0.x = pkh(a0.x, a0.y); P0.y = pkh(a0.z, a0.w);
        P0.z = pkh(a1.x, a1.y); P0.w = pkh(a1.z, a1.w);
        P1.x = pkh(a2.x, a2.y); P1.y = pkh(a2.z, a2.w);
        P1.z = (unsigned)ei[e];   // src at word 6
        P1.w = 0u;
        int pos = atomicAdd(&cursor[dst], 1);
        uint4* d = (uint4*)(csr + (size_t)pos * 8);
        d[0] = P0; d[1] = P1;
    }
}

// ---------------------------------------------------------------------------
// Gather aggregation, 8 nodes/wave, fused skip-add + bf16 output:
//   out16[i][0:64] = bf16( xf[i] + sum_{e: dst=i} relu(xf[src] + ea@W + b) )
// Round-5: force the 8-deep pipeline the compiler collapsed in round 4
// (VGPR_Count=20 proved every LOADE was sunk into its CONSUME):
//  - loads are UNCONDITIONAL with pos clamped to end-1 (straight-line code,
//    no guard for the compiler to merge with the consume guard);
//  - sched_barrier(0) after each LOADE pair pins issue order -> values must
//    stay live across the barrier -> real slot registers, ~24 VMEM in flight.
template <int D>
__global__ __launch_bounds__(256) void agg_gather(
    const float* __restrict__ xf32, const unsigned short* __restrict__ xf16,
    const unsigned int* __restrict__ cea,
    const float* __restrict__ ew, const float* __restrict__ eb,
    const int* __restrict__ rowptr,
    short* __restrict__ out) {
    int lane = threadIdx.x & 63;
    int wv = threadIdx.x >> 6;
    int i0 = (blockIdx.x * 4 + wv) * 8;
    if (i0 >= NN) return;
    float w0, w1, w2, w3, w4, w5, w6, w7, w8, w9, w10, w11, breg;
    if (D == 64 || lane < D) {
        w0 = ew[0 * D + lane];  w1 = ew[1 * D + lane];  w2 = ew[2 * D + lane];
        w3 = ew[3 * D + lane];  w4 = ew[4 * D + lane];  w5 = ew[5 * D + lane];
        w6 = ew[6 * D + lane];  w7 = ew[7 * D + lane];  w8 = ew[8 * D + lane];
        w9 = ew[9 * D + lane];  w10 = ew[10 * D + lane]; w11 = ew[11 * D + lane];
        breg = eb[lane];
    } else {
        w0=w1=w2=w3=w4=w5=w6=w7=w8=w9=w10=w11=0.f; breg = 0.f;
    }
    int rp = (lane <= 8) ? rowptr[i0 + lane] : 0;
    int beg = __builtin_amdgcn_readfirstlane(__builtin_amdgcn_readlane(rp, 0));
    int end = __builtin_amdgcn_readfirstlane(__builtin_amdgcn_readlane(rp, 8));
    int s0 = 0, s1 = 0;
    if (beg + lane < end) s0 = (int)cea[(size_t)(beg + lane) * 8 + 6];
    if (beg + 64 + lane < end) s1 = (int)cea[(size_t)(beg + 64 + lane) * 8 + 6];

    auto SKIPLD = [&](int j) -> float {
        if (D == HH) return h2f(xf16[(size_t)(i0 + j) * HH + lane]);
        return (lane < D) ? xf32[(size_t)(i0 + j) * ND + lane] : 0.f;
    };

    float acc = 0.f;
    int np = 0;
    int nb = __builtin_amdgcn_readlane(rp, 1);
    float sk = SKIPLD(0);
    while (np < 8 && nb == beg) {
        out[(size_t)(i0 + np) * 64 + lane] = f2bf(sk);   // acc == 0
        ++np;
        nb = (np < 8) ? __builtin_amdgcn_readlane(rp, np + 1) : 0x7fffffff;
        sk = (np < 8) ? SKIPLD(np) : 0.f;
    }

    // Unconditional load with clamp (valid because beg < end when called).
    auto LOADE = [&](int pos, uint4& P0, uint2& P1, float& XV) {
        int p = pos < end ? pos : end - 1;
        int off = p - beg;
        int src;
        if (off < 64)       src = __builtin_amdgcn_readlane(s0, off);
        else if (off < 128) src = __builtin_amdgcn_readlane(s1, off - 64);
        else                src = __builtin_amdgcn_readfirstlane((int)cea[(size_t)p * 8 + 6]);
        P0 = *(const uint4*)(cea + (size_t)p * 8);
        P1 = *(const uint2*)(cea + (size_t)p * 8 + 4);
        if (D == HH) XV = h2f(xf16[(size_t)src * HH + lane]);
        else         XV = (lane < D) ? xf32[(size_t)src * ND + lane] : 0.f;
    };
    auto CONSUME = [&](int pos, const uint4& P0, const uint2& P1, float XV) {
        if (pos < end) {
            float elin = breg;
            float2 e0 = upk(P0.x); elin = fmaf(e0.x, w0, elin);  elin = fmaf(e0.y, w1, elin);
            float2 e1 = upk(P0.y); elin = fmaf(e1.x, w2, elin);  elin = fmaf(e1.y, w3, elin);
            float2 e2 = upk(P0.z); elin = fmaf(e2.x, w4, elin);  elin = fmaf(e2.y, w5, elin);
            float2 e3 = upk(P0.w); elin = fmaf(e3.x, w6, elin);  elin = fmaf(e3.y, w7, elin);
            float2 e4 = upk(P1.x); elin = fmaf(e4.x, w8, elin);  elin = fmaf(e4.y, w9, elin);
            float2 e5 = upk(P1.y); elin = fmaf(e5.x, w10, elin); elin = fmaf(e5.y, w11, elin);
            acc += fmaxf(XV + elin, 0.f);
            int p1 = pos + 1;
            if (p1 == nb) {
                do {
                    out[(size_t)(i0 + np) * 64 + lane] = f2bf(acc + sk);
                    acc = 0.f; ++np;
                    nb = (np < 8) ? __builtin_amdgcn_readlane(rp, np + 1) : 0x7fffffff;
                    sk = (np < 8) ? SKIPLD(np) : 0.f;
                } while (p1 == nb);
            }
        }
    };

    if (beg >= end) return;   // all 8 nodes empty (already flushed above)

    uint4 A0, B0, C0, D0, E0, F0, G0, H0;
    uint2 A1, B1, C1, D1, E1, F1, G1, H1;
    float Ax, Bx, Cx, Dx, Ex, Fx, Gx, Hx;
    int base = beg;
    LOADE(base + 0, A0, A1, Ax);
    LOADE(base + 1, B0, B1, Bx);
    LOADE(base + 2, C0, C1, Cx);
    LOADE(base + 3, D0, D1, Dx);
    LOADE(base + 4, E0, E1, Ex);
    LOADE(base + 5, F0, F1, Fx);
    LOADE(base + 6, G0, G1, Gx);
    LOADE(base + 7, H0, H1, Hx);
    __builtin_amdgcn_sched_barrier(0);
    while (base < end) {
        CONSUME(base + 0, A0, A1, Ax);
        CONSUME(base + 1, B0, B1, Bx);
        LOADE(base + 8, A0, A1, Ax);
        LOADE(base + 9, B0, B1, Bx);
        __builtin_amdgcn_sched_barrier(0);
        if (base + 2 >= end) break;
        CONSUME(base + 2, C0, C1, Cx);
        CONSUME(base + 3, D0, D1, Dx);
        LOADE(base + 10, C0, C1, Cx);
        LOADE(base + 11, D0, D1, Dx);
        __builtin_amdgcn_sched_barrier(0);
        if (base + 4 >= end) break;
        CONSUME(base + 4, E0, E1, Ex);
        CONSUME(base + 5, F0, F1, Fx);
        LOADE(base + 12, E0, E1, Ex);
        LOADE(base + 13, F0, F1, Fx);
        __builtin_amdgcn_sched_barrier(0);
        if (base + 6 >= end) break;
        CONSUME(base + 6, G0, G1, Gx);
        CONSUME(base + 7, H0, H1, Hx);
        LOADE(base + 14, G0, G1, Gx);
        LOADE(base + 15, H0, H1, Hx);
        __builtin_amdgcn_sched_barrier(0);
        base += 8;
    }
}

// ---------------------------------------------------------------------------
// Node MLP 1: h = relu( relu(a @ w1a + b1a) @ w1b + b1b ), a = bf16[N][64] in.
// Persistent waves, register-resident weights (64 VGPR total), per-wave LDS.
#define HSTR1 68
__global__ __launch_bounds__(256, 3) void mlp1(
    const short* __restrict__ ain,
    const short* __restrict__ w1a_t, const float* __restrict__ b1a,
    const short* __restrict__ w1b_t, const float* __restrict__ b1b,
    unsigned short* __restrict__ h) {
    __shared__ float hid[4][16 * HSTR1];
    int lane = threadIdx.x & 63;
    int wv = threadIdx.x >> 6;
    int mrow = lane & 15, q = lane >> 4;
    float* hw = hid[wv];

    bf16x8 wa[4][2], wb[4][2];
    float ba[4], bb[4];
#pragma unroll
    for (int nt = 0; nt < 4; ++nt) {
        int n = nt * 16 + mrow;
        ba[nt] = b1a[n]; bb[nt] = b1b[n];
#pragma unroll
        for (int s = 0; s < 2; ++s) {
            wa[nt][s] = *(const bf16x8*)(w1a_t + n * 64 + s * 32 + q * 8);
            wb[nt][s] = *(const bf16x8*)(w1b_t + n * 64 + s * 32 + q * 8);
        }
    }

    int tile = blockIdx.x * 4 + wv;
    int stride = gridDim.x * 4;
    if (tile >= NTILE) return;
    bf16x8 a0 = *(const bf16x8*)(ain + (size_t)(tile * 16 + mrow) * 64 + q * 8);
    bf16x8 a1 = *(const bf16x8*)(ain + (size_t)(tile * 16 + mrow) * 64 + 32 + q * 8);
    while (true) {
        int nxt = tile + stride;
        bool more = nxt < NTILE;
        bf16x8 na0{}, na1{};
        if (more) {
            na0 = *(const bf16x8*)(ain + (size_t)(nxt * 16 + mrow) * 64 + q * 8);
            na1 = *(const bf16x8*)(ain + (size_t)(nxt * 16 + mrow) * 64 + 32 + q * 8);
        }
        int node0 = tile * 16;
#pragma unroll
        for (int nt = 0; nt < 4; ++nt) {
            f32x4 acc = {ba[nt], ba[nt], ba[nt], ba[nt]};
            acc = __builtin_amdgcn_mfma_f32_16x16x32_bf16(a0, wa[nt][0], acc, 0, 0, 0);
            acc = __builtin_amdgcn_mfma_f32_16x16x32_bf16(a1, wa[nt][1], acc, 0, 0, 0);
            int n = nt * 16 + mrow;
#pragma unroll
            for (int r = 0; r < 4; ++r)
                hw[(q * 4 + r) * HSTR1 + n] = fmaxf(acc[r], 0.f);
        }
        wave_lds_fence();
        bf16x8 af2[2];
#pragma unroll
        for (int s = 0; s < 2; ++s) {
            f32x4 v0 = *(const f32x4*)(hw + mrow * HSTR1 + s * 32 + q * 8);
            f32x4 v1 = *(const f32x4*)(hw + mrow * HSTR1 + s * 32 + q * 8 + 4);
#pragma unroll
            for (int j = 0; j < 4; ++j) { af2[s][j] = f2bf(v0[j]); af2[s][j + 4] = f2bf(v1[j]); }
        }
#pragma unroll
        for (int nt = 0; nt < 4; ++nt) {
            f32x4 acc = {bb[nt], bb[nt], bb[nt], bb[nt]};
            acc = __builtin_amdgcn_mfma_f32_16x16x32_bf16(af2[0], wb[nt][0], acc, 0, 0, 0);
            acc = __builtin_amdgcn_mfma_f32_16x16x32_bf16(af2[1], wb[nt][1], acc, 0, 0, 0);
            int n = nt * 16 + mrow;
#pragma unroll
            for (int r = 0; r < 4; ++r)
                h[(size_t)(node0 + q * 4 + r) * HH + n] = f2h(fmaxf(acc[r], 0.f));
        }
        if (!more) break;
        tile = nxt; a0 = na0; a1 = na1;
        wave_lds_fence();   // order this iter's hw reads vs next iter's writes
    }
}

// ---------------------------------------------------------------------------
// Node MLP 2 + fused mean-pool accumulate: input = bf16[N][64] (h+agg2 fused).
// Persistent waves (grid 512 = 2 blocks/CU). wa register-resident; w2b staged
// once per block into LDS (stride 136 shorts -> ~2-way bank alias, free).
#define HSTR2 132
#define WLSTR 136
__global__ __launch_bounds__(256, 2) void mlp2(
    const short* __restrict__ ain,
    const short* __restrict__ w2a_t, const float* __restrict__ b2a,
    const short* __restrict__ w2b_t, const float* __restrict__ b2b,
    const int* __restrict__ batch, float* __restrict__ sums) {
    __shared__ float buf[4][16 * HSTR2];
    __shared__ short wlds[EMB * WLSTR];
    int lane = threadIdx.x & 63;
    int wv = threadIdx.x >> 6;
    int mrow = lane & 15, q = lane >> 4;
    float* bw = buf[wv];

    // stage w2b -> LDS once per block (16384 shorts)
    for (int idx = threadIdx.x * 8; idx < EMB * EMB; idx += 2048) {
        int n = idx >> 7, k = idx & 127;
        *(bf16x8*)(wlds + n * WLSTR + k) = *(const bf16x8*)(w2b_t + idx);
    }

    bf16x8 wa[8][2];
    float ba[8], bb[8];
#pragma unroll
    for (int nt = 0; nt < 8; ++nt) {
        int n = nt * 16 + mrow;
        ba[nt] = b2a[n]; bb[nt] = b2b[n];
#pragma unroll
        for (int s = 0; s < 2; ++s)
            wa[nt][s] = *(const bf16x8*)(w2a_t + n * HH + s * 32 + q * 8);
    }
    __syncthreads();   // once: wlds visible to all waves

    int tile = blockIdx.x * 4 + wv;
    int stride = gridDim.x * 4;
    if (tile >= NTILE) return;
    bf16x8 a0 = *(const bf16x8*)(ain + (size_t)(tile * 16 + mrow) * 64 + q * 8);
    bf16x8 a1 = *(const bf16x8*)(ain + (size_t)(tile * 16 + mrow) * 64 + 32 + q * 8);
    int bv = (lane < 16) ? batch[tile * 16 + lane] : 0;
    while (true) {
        int nxt = tile + stride;
        bool more = nxt < NTILE;
        bf16x8 na0{}, na1{};
        int nbv = 0;
        if (more) {
            na0 = *(const bf16x8*)(ain + (size_t)(nxt * 16 + mrow) * 64 + q * 8);
            na1 = *(const bf16x8*)(ain + (size_t)(nxt * 16 + mrow) * 64 + 32 + q * 8);
            nbv = (lane < 16) ? batch[nxt * 16 + lane] : 0;
        }
        // GEMM1: 64 -> 128, relu, to LDS (transpose staging)
#pragma unroll
        for (int nt = 0; nt < 8; ++nt) {
            f32x4 acc = {ba[nt], ba[nt], ba[nt], ba[nt]};
            acc = __builtin_amdgcn_mfma_f32_16x16x32_bf16(a0, wa[nt][0], acc, 0, 0, 0);
            acc = __builtin_amdgcn_mfma_f32_16x16x32_bf16(a1, wa[nt][1], acc, 0, 0, 0);
            int n = nt * 16 + mrow;
#pragma unroll
            for (int r = 0; r < 4; ++r)
                bw[(q * 4 + r) * HSTR2 + n] = fmaxf(acc[r], 0.f);
        }
        wave_lds_fence();
        bf16x8 af2[4];
#pragma unroll
        for (int s = 0; s < 4; ++s) {
            f32x4 v0 = *(const f32x4*)(bw + mrow * HSTR2 + s * 32 + q * 8);
            f32x4 v1 = *(const f32x4*)(bw + mrow * HSTR2 + s * 32 + q * 8 + 4);
#pragma unroll
            for (int j = 0; j < 4; ++j) { af2[s][j] = f2bf(v0[j]); af2[s][j + 4] = f2bf(v1[j]); }
        }
        // GEMM2: 128 -> 128, B-fragments streamed from LDS, raw acc to LDS
#pragma unroll
        for (int nt = 0; nt < 8; ++nt) {
            f32x4 acc = {bb[nt], bb[nt], bb[nt], bb[nt]};
#pragma unroll
            for (int s = 0; s < 4; ++s) {
                bf16x8 bfrag = *(const bf16x8*)(wlds + (nt * 16 + mrow) * WLSTR + s * 32 + q * 8);
                acc = __builtin_amdgcn_mfma_f32_16x16x32_bf16(af2[s], bfrag, acc, 0, 0, 0);
            }
#pragma unroll
            for (int r = 0; r < 4; ++r)
                bw[(q * 4 + r) * HSTR2 + nt * 16 + mrow] = acc[r];
        }
        wave_lds_fence();
        // fused mean-pool accumulate (batch sorted -> few runs per tile)
#pragma unroll
        for (int cp = 0; cp < 2; ++cp) {
            int col = lane + cp * 64;
            float run = 0.f;
            int bprev = __shfl(bv, 0);
            for (int i = 0; i < 16; ++i) {
                int bg = __shfl(bv, i);
                if (bg != bprev) {
                    atomicAdd(&sums[bprev * EMB + col], run);
                    run = 0.f; bprev = bg;
                }
                run += bw[i * HSTR2 + col];
            }
            atomicAdd(&sums[bprev * EMB + col], run);
        }
        if (!more) break;
        tile = nxt; a0 = na0; a1 = na1; bv = nbv;
        wave_lds_fence();   // order pooling reads vs next iter's GEMM1 writes
    }
}

// ---------------------------------------------------------------------------
__global__ __launch_bounds__(128) void finalize(
    const float* __restrict__ sums, const int* __restrict__ batch,
    float* __restrict__ out) {
    int g = blockIdx.x;
    __shared__ int cnt_s;
    if (threadIdx.x == 0) {
        int lo = 0, hi = NN;
        while (lo < hi) { int mid = (lo + hi) >> 1; if (batch[mid] < g) lo = mid + 1; else hi = mid; }
        int lo2 = lo, hi2 = NN;
        while (lo2 < hi2) { int mid = (lo2 + hi2) >> 1; if (batch[mid] < g + 1) lo2 = mid + 1; else hi2 = mid; }
        cnt_s = lo2 - lo;
    }
    __syncthreads();
    int c = cnt_s > 1 ? cnt_s : 1;
    out[g * EMB + threadIdx.x] = sums[g * EMB + threadIdx.x] / (float)c;
}

// ---------------------------------------------------------------------------
extern "C" void kernel_launch(void* const* d_in, const int* in_sizes, int n_in,
                              void* d_out, int out_size, void* d_ws, size_t ws_size,
                              hipStream_t stream) {
    const float* x    = (const float*)d_in[0];
    const float* ea   = (const float*)d_in[1];
    const int*   ei   = (const int*)d_in[2];
    const int*   batch= (const int*)d_in[3];
    const float* el1w = (const float*)d_in[4];
    const float* el1b = (const float*)d_in[5];
    const float* w1a  = (const float*)d_in[6];
    const float* b1a  = (const float*)d_in[7];
    const float* w1b  = (const float*)d_in[8];
    const float* b1b  = (const float*)d_in[9];
    const float* el2w = (const float*)d_in[10];
    const float* el2b = (const float*)d_in[11];
    const float* w2a  = (const float*)d_in[12];
    const float* b2a  = (const float*)d_in[13];
    const float* w2b  = (const float*)d_in[14];
    const float* b2b  = (const float*)d_in[15];

    char* ws = (char*)d_ws;
    short*          aggout = (short*)ws;                    // [N][64] bf16 (64,000,000 B), both layers
    unsigned short* hbuf16 = (unsigned short*)(ws + 64000000); // [N][64] fp16 (64,000,000 B)
    unsigned int*   csr32  = (unsigned int*)(ws + 128000000);  // [E] 32B rows (64,000,000 B)
    int*   rowptr = (int*)(ws + 192000000);                 // N+1
    int*   cursor = (int*)(ws + 194000064);                 // N
    int*   deg    = (int*)(ws + 196000064);                 // N
    int*   bsum   = (int*)(ws + 198000064);                 // NBLK
    int*   boff   = (int*)(ws + 198000576);                 // NBLK
    float* sums   = (float*)(ws + 198001088);               // G*128 f32
    short* wts    = (short*)(ws + 206389696);               // 32768 shorts
    short* w1a_t = wts;
    short* w1b_t = wts + 4096;
    short* w2a_t = wts + 8192;
    short* w2b_t = wts + 16384;

    hipMemsetAsync(deg, 0, (size_t)NN * 4, stream);
    hipMemsetAsync(sums, 0, (size_t)GG * EMB * 4, stream);

    prep_weights<<<128, 256, 0, stream>>>(w1a, w1b, w2a, w2b, wts);
    // CSR build (+ fp16 attr pack + src fused into 32B rows)
    hist_kernel<<<(EE + 255) / 256, 256, 0, stream>>>(ei, deg);
    scan_reduce<<<NBLK, 256, 0, stream>>>(deg, bsum);
    scan_mid<<<1, 128, 0, stream>>>(bsum, boff, rowptr);
    scan_final<<<NBLK, 256, 0, stream>>>(deg, boff, rowptr, cursor);
    scatter_kernel<<<(EE + 255) / 256, 256, 0, stream>>>(ei, ea, cursor, csr32);
    // Layer 1
    agg_gather<ND><<<NN / 32, 256, 0, stream>>>(x, nullptr, csr32, el1w, el1b, rowptr, aggout);
    mlp1<<<1024, 256, 0, stream>>>(aggout, w1a_t, b1a, w1b_t, b1b, hbuf16);
    // Layer 2
    agg_gather<HH><<<NN / 32, 256, 0, stream>>>(nullptr, hbuf16, csr32, el2w, el2b, rowptr, aggout);
    mlp2<<<512, 256, 0, stream>>>(aggout, w2a_t, b2a, w2b_t, b2b, batch, sums);
    finalize<<<GG, 128, 0, stream>>>(sums, batch, (float*)d_out);
}